// Round 9
// baseline (29.209 us; speedup 1.0000x reference)
//
#include <hip/hip_runtime.h>
#include <hip/hip_bf16.h>

#define BS 32
#define NQ 300
#define NC 92
#define NT 50
#define Q_TOT (BS * NQ)   // 9600
#define T_TOT (BS * NT)   // 1600
#define QPB 8             // q-rows per tile (9600 = 1200 * 8)
#define TPB 320           // threads per block = targets per tile
#define N_TILES 6000      // (T_TOT/TPB) * (Q_TOT/QPB) = 5 * 1200
#define PERSIST 1500      // persistent blocks; each handles N_TILES/PERSIST = 4 tiles

typedef float f2 __attribute__((ext_vector_type(2)));

static __device__ __forceinline__ f2 fma2(f2 a, f2 b, f2 c) {
    return __builtin_elementwise_fma(a, b, c);
}
static __device__ __forceinline__ f2 max2(f2 a, f2 b) {
    return __builtin_elementwise_max(a, b);
}
static __device__ __forceinline__ f2 abs2(f2 a) {
    return __builtin_elementwise_abs(a);
}

// K1: one wave per query row. Softmax stats + SoA q-side repack:
//   ws layout: qcx | qcy | qhw(=w/2) | qhh(=h/2) | qar | qm | qinv, each [Q_TOT]
__global__ __launch_bounds__(256) void prep_kernel(
    const float* __restrict__ logits,   // [Q_TOT, NC]
    const float* __restrict__ boxes,    // [Q_TOT, 4] cxcywh
    float* __restrict__ ws)
{
    const int row  = blockIdx.x * 4 + (threadIdx.x >> 6);
    const int lane = threadIdx.x & 63;

    const float* rp = logits + (size_t)row * NC;
    float x0 = (lane < NC)      ? rp[lane]      : -INFINITY;
    float x1 = (lane + 64 < NC) ? rp[lane + 64] : -INFINITY;

    float m = fmaxf(x0, x1);
    #pragma unroll
    for (int off = 1; off < 64; off <<= 1)
        m = fmaxf(m, __shfl_xor(m, off));

    float s = __expf(x0 - m) + __expf(x1 - m);   // exp(-inf - m) == 0
    #pragma unroll
    for (int off = 1; off < 64; off <<= 1)
        s += __shfl_xor(s, off);

    if (lane == 0) {
        const float4 b = *reinterpret_cast<const float4*>(boxes + 4 * row);
        ws[0 * Q_TOT + row] = b.x;               // qcx
        ws[1 * Q_TOT + row] = b.y;               // qcy
        ws[2 * Q_TOT + row] = 0.5f * b.z;        // qhw
        ws[3 * Q_TOT + row] = 0.5f * b.w;        // qhh
        ws[4 * Q_TOT + row] = b.z * b.w;         // qar
        ws[5 * Q_TOT + row] = m;                 // qm
        ws[6 * Q_TOT + row] = 1.0f / s;          // qinv
    }
}

// K2: PERSISTENT version of R7's pk cost kernel. 1500 blocks, each walks 4
// tiles (tile = persistent slot + k*PERSIST). Inner body identical to R7.
__global__ __launch_bounds__(TPB) void cost_kernel_pk(
    const float* __restrict__ logits,       // [Q_TOT, NC]
    const int*   __restrict__ tgt_labels,   // [T_TOT]
    const float* __restrict__ tgt_boxes,    // [T_TOT, 4] cxcywh
    const float* __restrict__ ws,           // SoA q-tables (see K1)
    float* __restrict__ out)                // [Q_TOT, T_TOT]
{
    const float* qcx_t = ws + 0 * Q_TOT;
    const float* qcy_t = ws + 1 * Q_TOT;
    const float* qhw_t = ws + 2 * Q_TOT;
    const float* qhh_t = ws + 3 * Q_TOT;
    const float* qar_t = ws + 4 * Q_TOT;
    const float* qm_t  = ws + 5 * Q_TOT;
    const float* qiv_t = ws + 6 * Q_TOT;

    const f2 two = {2.0f, 2.0f};
    const f2 zero = {0.0f, 0.0f};

    #pragma unroll
    for (int k = 0; k < N_TILES / PERSIST; ++k) {
        const int tile = blockIdx.x + k * PERSIST;
        const int bx = tile % 5;                 // t-chunk
        const int by = tile / 5;                 // q-chunk

        const int t  = bx * TPB + threadIdx.x;
        const int q0 = by * QPB;

        // t-side, broadcast into both pk halves
        const float4 tb = *reinterpret_cast<const float4*>(tgt_boxes + 4 * t);
        const f2 tcx = {tb.x, tb.x};
        const f2 tcy = {tb.y, tb.y};
        const f2 thw = {0.5f * tb.z, 0.5f * tb.z};
        const f2 thh = {0.5f * tb.w, 0.5f * tb.w};
        const f2 tar = {tb.z * tb.w, tb.z * tb.w};
        const int lbl = tgt_labels[t];

        const float* lp = logits + (size_t)q0 * NC + lbl;
        float* op = out + (size_t)q0 * T_TOT + t;

        #pragma unroll
        for (int p = 0; p < QPB / 2; ++p) {
            const int q = q0 + 2 * p;

            const f2 qcx = *reinterpret_cast<const f2*>(qcx_t + q);
            const f2 qcy = *reinterpret_cast<const f2*>(qcy_t + q);
            const f2 qhw = *reinterpret_cast<const f2*>(qhw_t + q);
            const f2 qhh = *reinterpret_cast<const f2*>(qhh_t + q);
            const f2 qar = *reinterpret_cast<const f2*>(qar_t + q);
            const f2 qm  = *reinterpret_cast<const f2*>(qm_t  + q);
            const f2 qiv = *reinterpret_cast<const f2*>(qiv_t + q);

            const f2 lg = {lp[184 * p], lp[184 * p + NC]};

            const f2 ux = qcx - tcx,  uy = qcy - tcy;
            const f2 vx = qhw - thw,  vy = qhh - thh;
            const f2 hx = qhw + thw,  hy = qhh + thh;
            const f2 aux = abs2(ux), auy = abs2(uy);
            const f2 avx = abs2(vx), avy = abs2(vy);
            const f2 mx = max2(aux, avx), my = max2(auy, avy);
            const f2 dx = hx - mx, dy = hy - my;
            const f2 iw = max2(dx, zero), ih = max2(dy, zero);
            const f2 ew = fma2(two, hx, -dx);
            const f2 eh = fma2(two, hy, -dy);

            const f2 inter = iw * ih;
            const f2 earea = ew * eh;
            const f2 uni   = (qar + tar) - inter;
            const f2 ue    = uni * earea;
            const f2 rc    = {__builtin_amdgcn_rcpf(ue.x), __builtin_amdgcn_rcpf(ue.y)};
            const f2 giou  = fma2(uni, uni, inter * earea - ue) * rc;

            const f2 l1 = fma2(two, avx, aux) + fma2(two, avy, auy);

            const f2 pe = lg - qm;
            f2 prob = {__expf(pe.x), __expf(pe.y)};
            prob *= qiv;

            const f2 res = l1 - prob - giou;
            op[3200 * p]        = res.x;   // row q
            op[3200 * p + 1600] = res.y;   // row q+1
        }
    }
}

extern "C" void kernel_launch(void* const* d_in, const int* in_sizes, int n_in,
                              void* d_out, int out_size, void* d_ws, size_t ws_size,
                              hipStream_t stream) {
    const float* pred_logits = (const float*)d_in[0]; // [32,300,92]
    const float* pred_boxes  = (const float*)d_in[1]; // [32,300,4]
    const int*   tgt_labels  = (const int*)d_in[2];   // [32,50]
    const float* tgt_boxes   = (const float*)d_in[3]; // [32,50,4]
    float* out = (float*)d_out;                       // [32,300,1600]
    float* ws  = (float*)d_ws;                        // 7 * 9600 f32 = 262.5 KB

    prep_kernel<<<Q_TOT / 4, 256, 0, stream>>>(pred_logits, pred_boxes, ws);

    cost_kernel_pk<<<PERSIST, TPB, 0, stream>>>(pred_logits, tgt_labels,
                                                tgt_boxes, ws, out);
}